// Round 11
// baseline (151.764 us; speedup 1.0000x reference)
//
#include <hip/hip_runtime.h>
#include <math.h>

#define NN 20000   // nodes
#define NE 40000   // edges
#define H 64
#define F_ATOM 62
#define F_BOND 6
#define NB 512     // graphs

typedef _Float16 f16x8 __attribute__((ext_vector_type(8)));
typedef float f32x16 __attribute__((ext_vector_type(16)));

__device__ __forceinline__ float selu_f(float x) {
    const float scale = 1.0507009873554805f;
    const float alpha = 1.6732632423543772f;
    return scale * (x > 0.0f ? x : alpha * (__expf(x) - 1.0f));
}

__device__ __forceinline__ f16x8 splat8h(_Float16 x) {
    union { _Float16 h[2]; unsigned u; } p;
    p.h[0] = x; p.h[1] = x;
    union { unsigned u[4]; f16x8 v; } r;
    r.u[0] = p.u; r.u[1] = p.u; r.u[2] = p.u; r.u[3] = p.u;
    return r.v;
}

// Fused prep, role by blockIdx (256 threads each)  — round-8 verbatim (PASSED):
// [0,625)      : mlp2[kkpair][e] = packed f16x2 {relu(ef@Wm+bm)[2p], [2p+1]} via LDS transpose
// [625,5625)   : h = pad(nf) f32 + h_h f16 mirror
// [5625,5753)  : ewb = f16(Ew) in B-fragment-linear order
// [5753,7003)  : zero msg; [7003,7035): zero gsum
__global__ void prep_kernel(const float* __restrict__ nf, const float* __restrict__ ef,
                            const float* __restrict__ Wm, const float* __restrict__ bm,
                            const float* __restrict__ Ew,
                            float* __restrict__ h, _Float16* __restrict__ h_h,
                            unsigned* __restrict__ mlp2, _Float16* __restrict__ ewb,
                            float* __restrict__ msg, float* __restrict__ gsum) {
    const int bid = blockIdx.x;
    const int t = threadIdx.x;
    if (bid < 625) {
        __shared__ float st[64][65];
        const int el = t & 63;
        const int ig = t >> 6;                 // wave id; i = ig*16+p wave-uniform
        const int e = bid * 64 + el;
        const float* efe = ef + e * F_BOND;
        const float e0 = efe[0], e1 = efe[1], e2 = efe[2];
        const float e3 = efe[3], e4 = efe[4], e5 = efe[5];
#pragma unroll
        for (int p = 0; p < 16; ++p) {
            const int i = ig * 16 + p;
            float s = bm[i];
            s = fmaf(e0, Wm[0 * H + i], s);
            s = fmaf(e1, Wm[1 * H + i], s);
            s = fmaf(e2, Wm[2 * H + i], s);
            s = fmaf(e3, Wm[3 * H + i], s);
            s = fmaf(e4, Wm[4 * H + i], s);
            s = fmaf(e5, Wm[5 * H + i], s);
            st[i][el] = fmaxf(s, 0.0f);
        }
        __syncthreads();
        const int p = t >> 3;                  // kk-pair 0..31
        const int ch = t & 7;                  // 8-edge chunk
#pragma unroll
        for (int j = 0; j < 8; ++j) {
            const int e_l = ch * 8 + j;
            union { unsigned u; _Float16 hh[2]; } pk;
            pk.hh[0] = (_Float16)st[2 * p][e_l];
            pk.hh[1] = (_Float16)st[2 * p + 1][e_l];
            mlp2[(size_t)p * NE + bid * 64 + e_l] = pk.u;
        }
    } else if (bid < 5625) {
        int idx = (bid - 625) * 256 + t;
        int n = idx >> 6, c = idx & 63;
        float v = (c < F_ATOM) ? nf[n * F_ATOM + c] : 0.0f;
        h[idx] = v;
        h_h[idx] = (_Float16)v;
    } else if (bid < 5753) {
        int tid = (bid - 5625) * 256 + t;      // 0..32767
        int l = tid & 63;
        int nt = (tid >> 6) & 1;
        int c = tid >> 7;                      // 0..255 = kk*4 + cq
        int kk = c >> 2;
        int jbase = (c & 3) * 16 + (l >> 5) * 8;
        int i = nt * 32 + (l & 31);
        const float* src = Ew + kk * 4096 + i * 64 + jbase;
        _Float16* dst = ewb + tid * 8;
#pragma unroll
        for (int u = 0; u < 8; ++u) dst[u] = (_Float16)src[u];
    } else if (bid < 7003) {
        int idx = (bid - 5753) * 256 + t;
        reinterpret_cast<float4*>(msg)[idx] = make_float4(0.f, 0.f, 0.f, 0.f);
    } else {
        int idx = (bid - 7003) * 256 + t;
        reinterpret_cast<float4*>(gsum)[idx] = make_float4(0.f, 0.f, 0.f, 0.f);
    }
}

// Edge message. Grid = 1250: block b handles edges [(b>>1)*64, +64) and K-HALF
// kh = b&1 (kk in [kh*32, kh*32+32)). Block = 128 thr = 2 waves; wave kg owns
// 16 kk; each wave does M=64 (2 M-tiles, 4 accs) so each staged B-fragment is
// read once and feeds 2 MFMAs. 16-step chain per block (vs 32): per kk-step
// __syncthreads (drains prev DMA) -> stage next 8KB -> compute. 4.9 chains/CU.
// K-quarter partials merged in LDS; one atomic round per block (2 per edge total).
// A-build / B byte-layout / C/D row formula: round-8/9/10 verbatim (PASSED, 6.1e-5).
__global__ __launch_bounds__(128, 2) void edge_message_mfma(
    const _Float16* __restrict__ h_h, const unsigned* __restrict__ mlp2,
    const int* __restrict__ ed, const int* __restrict__ er,
    const _Float16* __restrict__ ewb, float* __restrict__ msg)
{
    __shared__ float4 smem4[2048];        // 32 KB: stage [2 kg][2 buf][8 KB]; merge reuses 16 KB
    __shared__ int edom_s[64];

    const int t = threadIdx.x;
    const int lane = t & 63;
    const int kg = t >> 6;                // K-group 0..1 within this block's half
    const int l31 = lane & 31;
    const int hf = lane >> 5;
    const int kh = blockIdx.x & 1;        // K-half 0..1
    const int eb = (blockIdx.x >> 1) * 64;
    const int kbase = kh * 32 + kg * 16;  // this wave's kk range: [kbase, kbase+16)

    if (t < 64) edom_s[t] = ed[eb + t];

    const int eA = eb + l31;              // M-tile 0 row (exact: 625*64 == NE)
    const int eB = eA + 32;               // M-tile 1 row
    const int gA = er[eA], gB = er[eB];

    // hj fragments (f16): j = cq*16 + hf*8 + tt   (proven mapping)
    f16x8 hjA[4], hjB[4];
#pragma unroll
    for (int cq = 0; cq < 4; ++cq) {
        hjA[cq] = *reinterpret_cast<const f16x8*>(h_h + gA * 64 + cq * 16 + hf * 8);
        hjB[cq] = *reinterpret_cast<const f16x8*>(h_h + gB * 64 + cq * 16 + hf * 8);
    }

    // mlp pairs: wave covers pairs [kbase/2, kbase/2 + 8); pair pp -> kk {kbase+2pp, +1}
    unsigned mvA[8], mvB[8];
#pragma unroll
    for (int pp = 0; pp < 8; ++pp) {
        mvA[pp] = mlp2[(size_t)((kbase >> 1) + pp) * NE + eA];
        mvB[pp] = mlp2[(size_t)((kbase >> 1) + pp) * NE + eB];
    }

    char* sm = reinterpret_cast<char*>(smem4);
    // stage 8KB slice kk = kbase+s into buf (kg*2 + (s&1)); whole wave stages it
    auto stage = [&](int s) {
        const char* gs = reinterpret_cast<const char*>(ewb) +
                         ((size_t)(kbase + s) << 13) + lane * 16;
        char* lb = sm + ((size_t)(kg * 2 + (s & 1)) << 13) + lane * 16;
#pragma unroll
        for (int r = 0; r < 8; ++r) {
            __builtin_amdgcn_global_load_lds(
                (const __attribute__((address_space(1))) void*)(gs + r * 1024),
                (__attribute__((address_space(3))) void*)(lb + r * 1024),
                16, 0, 0);
        }
    };

    f32x16 a00, a01, a10, a11;
#pragma unroll
    for (int i = 0; i < 16; ++i) { a00[i] = 0.f; a01[i] = 0.f; a10[i] = 0.f; a11[i] = 0.f; }

    stage(0);

#pragma unroll
    for (int s = 0; s < 16; ++s) {
        __syncthreads();                  // stage(s) DMA drained (own vmcnt) + barrier
        if (s < 15) stage(s + 1);         // lands during compute(s)
        const char* buf = sm + ((size_t)(kg * 2 + (s & 1)) << 13);
        union { unsigned u; _Float16 hh[2]; } ua, ub;
        ua.u = mvA[s >> 1]; ub.u = mvB[s >> 1];
        f16x8 sA = splat8h(ua.hh[s & 1]);
        f16x8 sB = splat8h(ub.hh[s & 1]);
#pragma unroll
        for (int cq = 0; cq < 4; ++cq) {
            f16x8 b0 = *reinterpret_cast<const f16x8*>(buf + (cq * 2 + 0) * 1024 + lane * 16);
            f16x8 b1 = *reinterpret_cast<const f16x8*>(buf + (cq * 2 + 1) * 1024 + lane * 16);
            f16x8 aA = sA * hjA[cq];
            f16x8 aB = sB * hjB[cq];
            a00 = __builtin_amdgcn_mfma_f32_32x32x16_f16(aA, b0, a00, 0, 0, 0);
            a01 = __builtin_amdgcn_mfma_f32_32x32x16_f16(aA, b1, a01, 0, 0, 0);
            a10 = __builtin_amdgcn_mfma_f32_32x32x16_f16(aB, b0, a10, 0, 0, 0);
            a11 = __builtin_amdgcn_mfma_f32_32x32x16_f16(aB, b1, a11, 0, 0, 0);
        }
    }

    // ---- K-quarter merge in LDS (stage area now dead) ----
    // C/D row formula (proven): m = (r&3) + 8*(r>>2) + 4*hf
    float* X = reinterpret_cast<float*>(smem4);        // 16 KB: [64 e_loc][64 col]
    __syncthreads();                      // all reads of stage LDS complete
    if (kg == 1) {
#pragma unroll
        for (int r = 0; r < 16; ++r) {
            const int m = (r & 3) + 8 * (r >> 2) + 4 * hf;
            X[m * 64 + l31]             = a00[r];
            X[m * 64 + 32 + l31]        = a01[r];
            X[(32 + m) * 64 + l31]      = a10[r];
            X[(32 + m) * 64 + 32 + l31] = a11[r];
        }
    }
    __syncthreads();
    if (kg == 0) {
#pragma unroll
        for (int r = 0; r < 16; ++r) {
            const int m = (r & 3) + 8 * (r >> 2) + 4 * hf;
            const int domA = edom_s[m];
            const int domB = edom_s[32 + m];
            atomicAdd(&msg[domA * 64 + l31],      a00[r] + X[m * 64 + l31]);
            atomicAdd(&msg[domA * 64 + 32 + l31], a01[r] + X[m * 64 + 32 + l31]);
            atomicAdd(&msg[domB * 64 + l31],      a10[r] + X[(32 + m) * 64 + l31]);
            atomicAdd(&msg[domB * 64 + 32 + l31], a11[r] + X[(32 + m) * 64 + 32 + l31]);
        }
    }
}

// h[n,i] = selu(msg[n] @ Wu + bu[i] + h[n,i]); h_h mirror; zeroes msg (round-8 verbatim)
__global__ void node_update_kernel(float* __restrict__ msg, const float* __restrict__ Wu,
                                   const float* __restrict__ bu, float* __restrict__ h,
                                   _Float16* __restrict__ h_h) {
    __shared__ float ms[4][68];
    int t = threadIdx.x;
    int nb = blockIdx.x * 4;
    int ln = t >> 6, i = t & 63;
    int o = (nb + ln) * H + i;
    ms[ln][i] = msg[o];
    msg[o] = 0.0f;                       // ready for next edge_message / replay
    __syncthreads();
    float s = bu[i];
#pragma unroll
    for (int k = 0; k < H; ++k) s = fmaf(ms[ln][k], Wu[k * H + i], s);
    float v = selu_f(s + h[o]);
    h[o] = v;
    h_h[o] = (_Float16)v;
}

// fused: ae = h@Wae+bae; aa = selu(ae@WR+bR); atomicAdd gsum[gid[n]]   (round-8 verbatim)
__global__ void embed_readout_kernel(const float* __restrict__ h, const float* __restrict__ Wae,
                                     const float* __restrict__ bae, const float* __restrict__ WR,
                                     const float* __restrict__ bR, const int* __restrict__ gid,
                                     float* __restrict__ gsum) {
    __shared__ float hs[4][68];
    __shared__ float as_[4][68];
    int t = threadIdx.x;
    int nb = blockIdx.x * 4;
    int ln = t >> 6, i = t & 63;
    hs[ln][i] = h[(nb + ln) * H + i];
    __syncthreads();
    float s = bae[i];
#pragma unroll
    for (int k = 0; k < H; ++k) s = fmaf(hs[ln][k], Wae[k * H + i], s);
    as_[ln][i] = s;
    __syncthreads();
    float s2 = bR[i];
#pragma unroll
    for (int k = 0; k < H; ++k) s2 = fmaf(as_[ln][k], WR[k * H + i], s2);
    atomicAdd(&gsum[gid[nb + ln] * H + i], selu_f(s2));
}

// per graph: ge = tanh(gsum); mo = relu(ge @ Wmlp + bmlp); out = mo @ Wout + bout (round-8 verbatim)
__global__ void final_kernel(const float* __restrict__ gsum, const float* __restrict__ Wmlp,
                             const float* __restrict__ bmlp, const float* __restrict__ Wout,
                             const float* __restrict__ bout, float* __restrict__ out) {
    __shared__ float ge[64];
    int g = blockIdx.x, i = threadIdx.x;
    ge[i] = tanhf(gsum[g * H + i]);
    __syncthreads();
    float s = bmlp[i];
#pragma unroll
    for (int k = 0; k < H; ++k) s = fmaf(ge[k], Wmlp[k * H + i], s);
    float mo = fmaxf(s, 0.0f) * Wout[i];
#pragma unroll
    for (int off = 32; off > 0; off >>= 1) mo += __shfl_down(mo, off);
    if (i == 0) out[g] = mo + bout[0];
}

extern "C" void kernel_launch(void* const* d_in, const int* in_sizes, int n_in,
                              void* d_out, int out_size, void* d_ws, size_t ws_size,
                              hipStream_t stream) {
    const float* nf   = (const float*)d_in[0];
    const float* ef   = (const float*)d_in[1];
    const int*   ed   = (const int*)d_in[2];   // edge_domain (scatter dest)
    const int*   er   = (const int*)d_in[3];   // edge_range  (gather src)
    const int*   gid  = (const int*)d_in[4];
    const float* Wm   = (const float*)d_in[5];
    const float* bm   = (const float*)d_in[6];
    const float* Ew   = (const float*)d_in[7];
    const float* Wu0  = (const float*)d_in[8];
    const float* bu0  = (const float*)d_in[9];
    const float* Wu1  = (const float*)d_in[10];
    const float* bu1  = (const float*)d_in[11];
    const float* Wae  = (const float*)d_in[12];
    const float* bae  = (const float*)d_in[13];
    const float* WR   = (const float*)d_in[14];
    const float* bR   = (const float*)d_in[15];
    const float* Wmlp = (const float*)d_in[16];
    const float* bmlp = (const float*)d_in[17];
    const float* Wout = (const float*)d_in[18];
    const float* bout = (const float*)d_in[19];
    float* out = (float*)d_out;

    float* ws = (float*)d_ws;
    float*    h    = ws;                              // 1,280,000 f32
    float*    msg  = ws + 1280000;                    // 1,280,000 f32
    float*    gsum = ws + 2560000;                    // 32,768 f32
    unsigned* mlp2 = (unsigned*)(ws + 2592768);       // 32*40000 u32 (f16x2 pairs)
    _Float16* h_h  = (_Float16*)(ws + 3872768);       // 1,280,000 f16
    _Float16* ewb  = (_Float16*)(ws + 4512768);       // 262,144 f16

    prep_kernel<<<7035, 256, 0, stream>>>(nf, ef, Wm, bm, Ew, h, h_h, mlp2, ewb, msg, gsum);

    for (int stepi = 0; stepi < 2; ++stepi) {
        edge_message_mfma<<<1250, 128, 0, stream>>>(h_h, mlp2, ed, er, ewb, msg);
        node_update_kernel<<<NN / 4, 256, 0, stream>>>(msg, stepi ? Wu1 : Wu0,
                                                       stepi ? bu1 : bu0, h, h_h);
    }

    embed_readout_kernel<<<NN / 4, 256, 0, stream>>>(h, Wae, bae, WR, bR, gid, gsum);
    final_kernel<<<NB, 64, 0, stream>>>(gsum, Wmlp, bmlp, Wout, bout, out);
}

// Round 12
// 128.564 us; speedup vs baseline: 1.1805x; 1.1805x over previous
//
#include <hip/hip_runtime.h>
#include <math.h>

#define NN 20000   // nodes
#define NE 40000   // edges
#define H 64
#define F_ATOM 62
#define F_BOND 6
#define NB 512     // graphs

typedef _Float16 f16x8 __attribute__((ext_vector_type(8)));
typedef float f32x16 __attribute__((ext_vector_type(16)));

__device__ __forceinline__ float selu_f(float x) {
    const float scale = 1.0507009873554805f;
    const float alpha = 1.6732632423543772f;
    return scale * (x > 0.0f ? x : alpha * (__expf(x) - 1.0f));
}

__device__ __forceinline__ f16x8 splat8h(_Float16 x) {
    union { _Float16 h[2]; unsigned u; } p;
    p.h[0] = x; p.h[1] = x;
    union { unsigned u[4]; f16x8 v; } r;
    r.u[0] = p.u; r.u[1] = p.u; r.u[2] = p.u; r.u[3] = p.u;
    return r.v;
}

// Fused prep, role by blockIdx (256 threads each)  — round-8 verbatim (PASSED):
// [0,625)      : mlp2[kkpair][e] = packed f16x2 {relu(ef@Wm+bm)[2p], [2p+1]} via LDS transpose
// [625,5625)   : h = pad(nf) f32 + h_h f16 mirror
// [5625,5753)  : ewb = f16(Ew) in B-fragment-linear order
// [5753,7003)  : zero msg; [7003,7035): zero gsum
__global__ void prep_kernel(const float* __restrict__ nf, const float* __restrict__ ef,
                            const float* __restrict__ Wm, const float* __restrict__ bm,
                            const float* __restrict__ Ew,
                            float* __restrict__ h, _Float16* __restrict__ h_h,
                            unsigned* __restrict__ mlp2, _Float16* __restrict__ ewb,
                            float* __restrict__ msg, float* __restrict__ gsum) {
    const int bid = blockIdx.x;
    const int t = threadIdx.x;
    if (bid < 625) {
        __shared__ float st[64][65];
        const int el = t & 63;
        const int ig = t >> 6;                 // wave id; i = ig*16+p wave-uniform
        const int e = bid * 64 + el;
        const float* efe = ef + e * F_BOND;
        const float e0 = efe[0], e1 = efe[1], e2 = efe[2];
        const float e3 = efe[3], e4 = efe[4], e5 = efe[5];
#pragma unroll
        for (int p = 0; p < 16; ++p) {
            const int i = ig * 16 + p;
            float s = bm[i];
            s = fmaf(e0, Wm[0 * H + i], s);
            s = fmaf(e1, Wm[1 * H + i], s);
            s = fmaf(e2, Wm[2 * H + i], s);
            s = fmaf(e3, Wm[3 * H + i], s);
            s = fmaf(e4, Wm[4 * H + i], s);
            s = fmaf(e5, Wm[5 * H + i], s);
            st[i][el] = fmaxf(s, 0.0f);
        }
        __syncthreads();
        const int p = t >> 3;                  // kk-pair 0..31
        const int ch = t & 7;                  // 8-edge chunk
#pragma unroll
        for (int j = 0; j < 8; ++j) {
            const int e_l = ch * 8 + j;
            union { unsigned u; _Float16 hh[2]; } pk;
            pk.hh[0] = (_Float16)st[2 * p][e_l];
            pk.hh[1] = (_Float16)st[2 * p + 1][e_l];
            mlp2[(size_t)p * NE + bid * 64 + e_l] = pk.u;
        }
    } else if (bid < 5625) {
        int idx = (bid - 625) * 256 + t;
        int n = idx >> 6, c = idx & 63;
        float v = (c < F_ATOM) ? nf[n * F_ATOM + c] : 0.0f;
        h[idx] = v;
        h_h[idx] = (_Float16)v;
    } else if (bid < 5753) {
        int tid = (bid - 5625) * 256 + t;      // 0..32767
        int l = tid & 63;
        int nt = (tid >> 6) & 1;
        int c = tid >> 7;                      // 0..255 = kk*4 + cq
        int kk = c >> 2;
        int jbase = (c & 3) * 16 + (l >> 5) * 8;
        int i = nt * 32 + (l & 31);
        const float* src = Ew + kk * 4096 + i * 64 + jbase;
        _Float16* dst = ewb + tid * 8;
#pragma unroll
        for (int u = 0; u < 8; ++u) dst[u] = (_Float16)src[u];
    } else if (bid < 7003) {
        int idx = (bid - 5753) * 256 + t;
        reinterpret_cast<float4*>(msg)[idx] = make_float4(0.f, 0.f, 0.f, 0.f);
    } else {
        int idx = (bid - 7003) * 256 + t;
        reinterpret_cast<float4*>(gsum)[idx] = make_float4(0.f, 0.f, 0.f, 0.f);
    }
}

// Edge message. Block = 128 thr = 2 waves; wave kg owns kk [kg*32, kg*32+32)
// and a PRIVATE 3x8KB LDS ring. NO inter-wave barrier in the hot loop: each
// wave prefetches 2 slices ahead and waits only its own counted vmcnt(8)
// (T3+T4, per-wave form). M=64/wave (2 M-tiles, 4 accs): each staged fragment
// read once, feeds 2 MFMAs. Grid 625 exact; full K per block -> 1 atomic round.
// A-build / B byte-layout / C/D row formula / merge: round-10 verbatim (PASSED, 6.1e-5).
__global__ __launch_bounds__(128, 2) void edge_message_mfma(
    const _Float16* __restrict__ h_h, const unsigned* __restrict__ mlp2,
    const int* __restrict__ ed, const int* __restrict__ er,
    const _Float16* __restrict__ ewb, float* __restrict__ msg)
{
    __shared__ char sm[49152];            // 48 KB: wave kg -> [kg*24K, +24K) 3-buf ring; merge X reuses [0,16K)
    __shared__ int edom_s[64];

    const int t = threadIdx.x;
    const int lane = t & 63;
    const int kg = t >> 6;                // K-group 0..1 (kk in [kg*32, kg*32+32))
    const int l31 = lane & 31;
    const int hf = lane >> 5;
    const int eb = blockIdx.x * 64;

    if (t < 64) edom_s[t] = ed[eb + t];   // loaded by wave 0, read only by wave 0

    const int eA = eb + l31;              // M-tile 0 row (exact: 625*64 == NE)
    const int eB = eA + 32;               // M-tile 1 row
    const int gA = er[eA], gB = er[eB];

    // hj fragments (f16): j = cq*16 + hf*8 + tt   (proven mapping)
    f16x8 hjA[4], hjB[4];
#pragma unroll
    for (int cq = 0; cq < 4; ++cq) {
        hjA[cq] = *reinterpret_cast<const f16x8*>(h_h + gA * 64 + cq * 16 + hf * 8);
        hjB[cq] = *reinterpret_cast<const f16x8*>(h_h + gB * 64 + cq * 16 + hf * 8);
    }

    // mlp pairs: kg covers pairs [kg*16, kg*16+16); pair pp -> kk {2pp, 2pp+1}
    unsigned mvA[16], mvB[16];
#pragma unroll
    for (int pp = 0; pp < 16; ++pp) {
        mvA[pp] = mlp2[(size_t)(kg * 16 + pp) * NE + eA];
        mvB[pp] = mlp2[(size_t)(kg * 16 + pp) * NE + eB];
    }

    // drain pre-loads so vmcnt counts ONLY stage DMAs from here on
    asm volatile("s_waitcnt vmcnt(0)" ::: "memory");

    char* wbase = sm + kg * 24576;
    // stage 8KB slice kk = kg*32+s into private ring buf (s%3); whole wave stages it
    auto stage = [&](int s) {
        const char* gs = reinterpret_cast<const char*>(ewb) +
                         ((size_t)(kg * 32 + s) << 13) + lane * 16;
        char* lb = wbase + (s % 3) * 8192 + lane * 16;
#pragma unroll
        for (int r = 0; r < 8; ++r) {
            __builtin_amdgcn_global_load_lds(
                (const __attribute__((address_space(1))) void*)(gs + r * 1024),
                (__attribute__((address_space(3))) void*)(lb + r * 1024),
                16, 0, 0);
        }
    };

    f32x16 a00, a01, a10, a11;
#pragma unroll
    for (int i = 0; i < 16; ++i) { a00[i] = 0.f; a01[i] = 0.f; a10[i] = 0.f; a11[i] = 0.f; }

    stage(0);
    stage(1);                             // 16 DMA ops in flight

#pragma unroll
    for (int s = 0; s < 32; ++s) {
        if (s < 31) asm volatile("s_waitcnt vmcnt(8)" ::: "memory");  // stage(s) retired
        else        asm volatile("s_waitcnt vmcnt(0)" ::: "memory");  // last slice
        if (s < 30) stage(s + 2);         // buf (s+2)%3 == (s-1)%3, reads finished in iter s-1
        const char* buf = wbase + (s % 3) * 8192;
        union { unsigned u; _Float16 hh[2]; } ua, ub;
        ua.u = mvA[s >> 1]; ub.u = mvB[s >> 1];
        f16x8 sA = splat8h(ua.hh[s & 1]);
        f16x8 sB = splat8h(ub.hh[s & 1]);
#pragma unroll
        for (int cq = 0; cq < 4; ++cq) {
            f16x8 b0 = *reinterpret_cast<const f16x8*>(buf + (cq * 2 + 0) * 1024 + lane * 16);
            f16x8 b1 = *reinterpret_cast<const f16x8*>(buf + (cq * 2 + 1) * 1024 + lane * 16);
            f16x8 aA = sA * hjA[cq];
            f16x8 aB = sB * hjB[cq];
            a00 = __builtin_amdgcn_mfma_f32_32x32x16_f16(aA, b0, a00, 0, 0, 0);
            a01 = __builtin_amdgcn_mfma_f32_32x32x16_f16(aA, b1, a01, 0, 0, 0);
            a10 = __builtin_amdgcn_mfma_f32_32x32x16_f16(aB, b0, a10, 0, 0, 0);
            a11 = __builtin_amdgcn_mfma_f32_32x32x16_f16(aB, b1, a11, 0, 0, 0);
        }
    }

    // ---- K-partial merge in LDS (stage area now dead; all DMA drained) ----
    // C/D row formula (proven): m = (r&3) + 8*(r>>2) + 4*hf
    float* X = reinterpret_cast<float*>(sm);           // 16 KB: [64 e_loc][64 col]
    __syncthreads();                      // both waves done computing
    if (kg == 1) {
#pragma unroll
        for (int r = 0; r < 16; ++r) {
            const int m = (r & 3) + 8 * (r >> 2) + 4 * hf;
            X[m * 64 + l31]             = a00[r];
            X[m * 64 + 32 + l31]        = a01[r];
            X[(32 + m) * 64 + l31]      = a10[r];
            X[(32 + m) * 64 + 32 + l31] = a11[r];
        }
    }
    __syncthreads();
    if (kg == 0) {
#pragma unroll
        for (int r = 0; r < 16; ++r) {
            const int m = (r & 3) + 8 * (r >> 2) + 4 * hf;
            const int domA = edom_s[m];
            const int domB = edom_s[32 + m];
            atomicAdd(&msg[domA * 64 + l31],      a00[r] + X[m * 64 + l31]);
            atomicAdd(&msg[domA * 64 + 32 + l31], a01[r] + X[m * 64 + 32 + l31]);
            atomicAdd(&msg[domB * 64 + l31],      a10[r] + X[(32 + m) * 64 + l31]);
            atomicAdd(&msg[domB * 64 + 32 + l31], a11[r] + X[(32 + m) * 64 + 32 + l31]);
        }
    }
}

// h[n,i] = selu(msg[n] @ Wu + bu[i] + h[n,i]); h_h mirror; zeroes msg (round-8 verbatim)
__global__ void node_update_kernel(float* __restrict__ msg, const float* __restrict__ Wu,
                                   const float* __restrict__ bu, float* __restrict__ h,
                                   _Float16* __restrict__ h_h) {
    __shared__ float ms[4][68];
    int t = threadIdx.x;
    int nb = blockIdx.x * 4;
    int ln = t >> 6, i = t & 63;
    int o = (nb + ln) * H + i;
    ms[ln][i] = msg[o];
    msg[o] = 0.0f;                       // ready for next edge_message / replay
    __syncthreads();
    float s = bu[i];
#pragma unroll
    for (int k = 0; k < H; ++k) s = fmaf(ms[ln][k], Wu[k * H + i], s);
    float v = selu_f(s + h[o]);
    h[o] = v;
    h_h[o] = (_Float16)v;
}

// fused: ae = h@Wae+bae; aa = selu(ae@WR+bR); atomicAdd gsum[gid[n]]   (round-8 verbatim)
__global__ void embed_readout_kernel(const float* __restrict__ h, const float* __restrict__ Wae,
                                     const float* __restrict__ bae, const float* __restrict__ WR,
                                     const float* __restrict__ bR, const int* __restrict__ gid,
                                     float* __restrict__ gsum) {
    __shared__ float hs[4][68];
    __shared__ float as_[4][68];
    int t = threadIdx.x;
    int nb = blockIdx.x * 4;
    int ln = t >> 6, i = t & 63;
    hs[ln][i] = h[(nb + ln) * H + i];
    __syncthreads();
    float s = bae[i];
#pragma unroll
    for (int k = 0; k < H; ++k) s = fmaf(hs[ln][k], Wae[k * H + i], s);
    as_[ln][i] = s;
    __syncthreads();
    float s2 = bR[i];
#pragma unroll
    for (int k = 0; k < H; ++k) s2 = fmaf(as_[ln][k], WR[k * H + i], s2);
    atomicAdd(&gsum[gid[nb + ln] * H + i], selu_f(s2));
}

// per graph: ge = tanh(gsum); mo = relu(ge @ Wmlp + bmlp); out = mo @ Wout + bout (round-8 verbatim)
__global__ void final_kernel(const float* __restrict__ gsum, const float* __restrict__ Wmlp,
                             const float* __restrict__ bmlp, const float* __restrict__ Wout,
                             const float* __restrict__ bout, float* __restrict__ out) {
    __shared__ float ge[64];
    int g = blockIdx.x, i = threadIdx.x;
    ge[i] = tanhf(gsum[g * H + i]);
    __syncthreads();
    float s = bmlp[i];
#pragma unroll
    for (int k = 0; k < H; ++k) s = fmaf(ge[k], Wmlp[k * H + i], s);
    float mo = fmaxf(s, 0.0f) * Wout[i];
#pragma unroll
    for (int off = 32; off > 0; off >>= 1) mo += __shfl_down(mo, off);
    if (i == 0) out[g] = mo + bout[0];
}

extern "C" void kernel_launch(void* const* d_in, const int* in_sizes, int n_in,
                              void* d_out, int out_size, void* d_ws, size_t ws_size,
                              hipStream_t stream) {
    const float* nf   = (const float*)d_in[0];
    const float* ef   = (const float*)d_in[1];
    const int*   ed   = (const int*)d_in[2];   // edge_domain (scatter dest)
    const int*   er   = (const int*)d_in[3];   // edge_range  (gather src)
    const int*   gid  = (const int*)d_in[4];
    const float* Wm   = (const float*)d_in[5];
    const float* bm   = (const float*)d_in[6];
    const float* Ew   = (const float*)d_in[7];
    const float* Wu0  = (const float*)d_in[8];
    const float* bu0  = (const float*)d_in[9];
    const float* Wu1  = (const float*)d_in[10];
    const float* bu1  = (const float*)d_in[11];
    const float* Wae  = (const float*)d_in[12];
    const float* bae  = (const float*)d_in[13];
    const float* WR   = (const float*)d_in[14];
    const float* bR   = (const float*)d_in[15];
    const float* Wmlp = (const float*)d_in[16];
    const float* bmlp = (const float*)d_in[17];
    const float* Wout = (const float*)d_in[18];
    const float* bout = (const float*)d_in[19];
    float* out = (float*)d_out;

    float* ws = (float*)d_ws;
    float*    h    = ws;                              // 1,280,000 f32
    float*    msg  = ws + 1280000;                    // 1,280,000 f32
    float*    gsum = ws + 2560000;                    // 32,768 f32
    unsigned* mlp2 = (unsigned*)(ws + 2592768);       // 32*40000 u32 (f16x2 pairs)
    _Float16* h_h  = (_Float16*)(ws + 3872768);       // 1,280,000 f16
    _Float16* ewb  = (_Float16*)(ws + 4512768);       // 262,144 f16

    prep_kernel<<<7035, 256, 0, stream>>>(nf, ef, Wm, bm, Ew, h, h_h, mlp2, ewb, msg, gsum);

    for (int stepi = 0; stepi < 2; ++stepi) {
        edge_message_mfma<<<625, 128, 0, stream>>>(h_h, mlp2, ed, er, ewb, msg);
        node_update_kernel<<<NN / 4, 256, 0, stream>>>(msg, stepi ? Wu1 : Wu0,
                                                       stepi ? bu1 : bu0, h, h_h);
    }

    embed_readout_kernel<<<NN / 4, 256, 0, stream>>>(h, Wae, bae, WR, bR, gid, gsum);
    final_kernel<<<NB, 64, 0, stream>>>(gsum, Wmlp, bmlp, Wout, bout, out);
}

// Round 13
// 128.040 us; speedup vs baseline: 1.1853x; 1.0041x over previous
//
#include <hip/hip_runtime.h>
#include <math.h>

#define NN 20000   // nodes
#define NE 40000   // edges
#define H 64
#define F_ATOM 62
#define F_BOND 6
#define NB 512     // graphs

typedef _Float16 f16x8 __attribute__((ext_vector_type(8)));
typedef float f32x16 __attribute__((ext_vector_type(16)));

__device__ __forceinline__ float selu_f(float x) {
    const float scale = 1.0507009873554805f;
    const float alpha = 1.6732632423543772f;
    return scale * (x > 0.0f ? x : alpha * (__expf(x) - 1.0f));
}

__device__ __forceinline__ f16x8 splat8h(_Float16 x) {
    union { _Float16 h[2]; unsigned u; } p;
    p.h[0] = x; p.h[1] = x;
    union { unsigned u[4]; f16x8 v; } r;
    r.u[0] = p.u; r.u[1] = p.u; r.u[2] = p.u; r.u[3] = p.u;
    return r.v;
}

// Fused prep, role by blockIdx (256 threads each) — round-8 structure (PASSED),
// now h is f16-ONLY (no f32 mirror):
// [0,625)      : mlp2[kkpair][e] = packed f16x2 {relu(ef@Wm+bm)[2p], [2p+1]} via LDS transpose
// [625,5625)   : h_h = f16(pad(nf))
// [5625,5753)  : ewb = f16(Ew) in B-fragment-linear order
// [5753,7003)  : zero msg; [7003,7035): zero gsum
__global__ void prep_kernel(const float* __restrict__ nf, const float* __restrict__ ef,
                            const float* __restrict__ Wm, const float* __restrict__ bm,
                            const float* __restrict__ Ew,
                            _Float16* __restrict__ h_h,
                            unsigned* __restrict__ mlp2, _Float16* __restrict__ ewb,
                            float* __restrict__ msg, float* __restrict__ gsum) {
    const int bid = blockIdx.x;
    const int t = threadIdx.x;
    if (bid < 625) {
        __shared__ float st[64][65];
        const int el = t & 63;
        const int ig = t >> 6;                 // wave id; i = ig*16+p wave-uniform
        const int e = bid * 64 + el;
        const float* efe = ef + e * F_BOND;
        const float e0 = efe[0], e1 = efe[1], e2 = efe[2];
        const float e3 = efe[3], e4 = efe[4], e5 = efe[5];
#pragma unroll
        for (int p = 0; p < 16; ++p) {
            const int i = ig * 16 + p;
            float s = bm[i];
            s = fmaf(e0, Wm[0 * H + i], s);
            s = fmaf(e1, Wm[1 * H + i], s);
            s = fmaf(e2, Wm[2 * H + i], s);
            s = fmaf(e3, Wm[3 * H + i], s);
            s = fmaf(e4, Wm[4 * H + i], s);
            s = fmaf(e5, Wm[5 * H + i], s);
            st[i][el] = fmaxf(s, 0.0f);
        }
        __syncthreads();
        const int p = t >> 3;                  // kk-pair 0..31
        const int ch = t & 7;                  // 8-edge chunk
#pragma unroll
        for (int j = 0; j < 8; ++j) {
            const int e_l = ch * 8 + j;
            union { unsigned u; _Float16 hh[2]; } pk;
            pk.hh[0] = (_Float16)st[2 * p][e_l];
            pk.hh[1] = (_Float16)st[2 * p + 1][e_l];
            mlp2[(size_t)p * NE + bid * 64 + e_l] = pk.u;
        }
    } else if (bid < 5625) {
        int idx = (bid - 625) * 256 + t;
        int n = idx >> 6, c = idx & 63;
        h_h[idx] = (_Float16)((c < F_ATOM) ? nf[n * F_ATOM + c] : 0.0f);
    } else if (bid < 5753) {
        int tid = (bid - 5625) * 256 + t;      // 0..32767
        int l = tid & 63;
        int nt = (tid >> 6) & 1;
        int c = tid >> 7;                      // 0..255 = kk*4 + cq
        int kk = c >> 2;
        int jbase = (c & 3) * 16 + (l >> 5) * 8;
        int i = nt * 32 + (l & 31);
        const float* src = Ew + kk * 4096 + i * 64 + jbase;
        _Float16* dst = ewb + tid * 8;
#pragma unroll
        for (int u = 0; u < 8; ++u) dst[u] = (_Float16)src[u];
    } else if (bid < 7003) {
        int idx = (bid - 5753) * 256 + t;
        reinterpret_cast<float4*>(msg)[idx] = make_float4(0.f, 0.f, 0.f, 0.f);
    } else {
        int idx = (bid - 7003) * 256 + t;
        reinterpret_cast<float4*>(gsum)[idx] = make_float4(0.f, 0.f, 0.f, 0.f);
    }
}

// Edge message — round-12 verbatim (PASSED, 6.1e-5) + s_setprio(1) around the
// MFMA cluster (T5: barrier-free waves have role diversity). Block = 128 thr =
// 2 waves; wave kg owns kk [kg*32,+32) and a PRIVATE 3x8KB LDS ring; counted
// per-wave vmcnt(8), no inter-wave barrier in hot loop; LDS merge + 1 atomic round.
__global__ __launch_bounds__(128, 2) void edge_message_mfma(
    const _Float16* __restrict__ h_h, const unsigned* __restrict__ mlp2,
    const int* __restrict__ ed, const int* __restrict__ er,
    const _Float16* __restrict__ ewb, float* __restrict__ msg)
{
    __shared__ char sm[49152];            // 48 KB: wave kg -> [kg*24K, +24K) 3-buf ring; merge X reuses [0,16K)
    __shared__ int edom_s[64];

    const int t = threadIdx.x;
    const int lane = t & 63;
    const int kg = t >> 6;                // K-group 0..1 (kk in [kg*32, kg*32+32))
    const int l31 = lane & 31;
    const int hf = lane >> 5;
    const int eb = blockIdx.x * 64;

    if (t < 64) edom_s[t] = ed[eb + t];   // loaded by wave 0 (=kg 0), read only by kg 0

    const int eA = eb + l31;              // M-tile 0 row (exact: 625*64 == NE)
    const int eB = eA + 32;               // M-tile 1 row
    const int gA = er[eA], gB = er[eB];

    // hj fragments (f16): j = cq*16 + hf*8 + tt   (proven mapping)
    f16x8 hjA[4], hjB[4];
#pragma unroll
    for (int cq = 0; cq < 4; ++cq) {
        hjA[cq] = *reinterpret_cast<const f16x8*>(h_h + gA * 64 + cq * 16 + hf * 8);
        hjB[cq] = *reinterpret_cast<const f16x8*>(h_h + gB * 64 + cq * 16 + hf * 8);
    }

    // mlp pairs: kg covers pairs [kg*16, kg*16+16); pair pp -> kk {2pp, 2pp+1}
    unsigned mvA[16], mvB[16];
#pragma unroll
    for (int pp = 0; pp < 16; ++pp) {
        mvA[pp] = mlp2[(size_t)(kg * 16 + pp) * NE + eA];
        mvB[pp] = mlp2[(size_t)(kg * 16 + pp) * NE + eB];
    }

    // drain pre-loads so vmcnt counts ONLY stage DMAs from here on
    asm volatile("s_waitcnt vmcnt(0)" ::: "memory");

    char* wbase = sm + kg * 24576;
    // stage 8KB slice kk = kg*32+s into private ring buf (s%3); whole wave stages it
    auto stage = [&](int s) {
        const char* gs = reinterpret_cast<const char*>(ewb) +
                         ((size_t)(kg * 32 + s) << 13) + lane * 16;
        char* lb = wbase + (s % 3) * 8192 + lane * 16;
#pragma unroll
        for (int r = 0; r < 8; ++r) {
            __builtin_amdgcn_global_load_lds(
                (const __attribute__((address_space(1))) void*)(gs + r * 1024),
                (__attribute__((address_space(3))) void*)(lb + r * 1024),
                16, 0, 0);
        }
    };

    f32x16 a00, a01, a10, a11;
#pragma unroll
    for (int i = 0; i < 16; ++i) { a00[i] = 0.f; a01[i] = 0.f; a10[i] = 0.f; a11[i] = 0.f; }

    stage(0);
    stage(1);                             // 16 DMA ops in flight

#pragma unroll
    for (int s = 0; s < 32; ++s) {
        if (s < 31) asm volatile("s_waitcnt vmcnt(8)" ::: "memory");  // stage(s) retired
        else        asm volatile("s_waitcnt vmcnt(0)" ::: "memory");  // last slice
        if (s < 30) stage(s + 2);         // buf (s+2)%3 == (s-1)%3, reads finished in iter s-1
        const char* buf = wbase + (s % 3) * 8192;
        union { unsigned u; _Float16 hh[2]; } ua, ub;
        ua.u = mvA[s >> 1]; ub.u = mvB[s >> 1];
        f16x8 sA = splat8h(ua.hh[s & 1]);
        f16x8 sB = splat8h(ub.hh[s & 1]);
        __builtin_amdgcn_s_setprio(1);
#pragma unroll
        for (int cq = 0; cq < 4; ++cq) {
            f16x8 b0 = *reinterpret_cast<const f16x8*>(buf + (cq * 2 + 0) * 1024 + lane * 16);
            f16x8 b1 = *reinterpret_cast<const f16x8*>(buf + (cq * 2 + 1) * 1024 + lane * 16);
            f16x8 aA = sA * hjA[cq];
            f16x8 aB = sB * hjB[cq];
            a00 = __builtin_amdgcn_mfma_f32_32x32x16_f16(aA, b0, a00, 0, 0, 0);
            a01 = __builtin_amdgcn_mfma_f32_32x32x16_f16(aA, b1, a01, 0, 0, 0);
            a10 = __builtin_amdgcn_mfma_f32_32x32x16_f16(aB, b0, a10, 0, 0, 0);
            a11 = __builtin_amdgcn_mfma_f32_32x32x16_f16(aB, b1, a11, 0, 0, 0);
        }
        __builtin_amdgcn_s_setprio(0);
    }

    // ---- K-partial merge in LDS (stage area now dead; all DMA drained) ----
    // C/D row formula (proven): m = (r&3) + 8*(r>>2) + 4*hf
    float* X = reinterpret_cast<float*>(sm);           // 16 KB: [64 e_loc][64 col]
    __syncthreads();                      // both waves done computing
    if (kg == 1) {
#pragma unroll
        for (int r = 0; r < 16; ++r) {
            const int m = (r & 3) + 8 * (r >> 2) + 4 * hf;
            X[m * 64 + l31]             = a00[r];
            X[m * 64 + 32 + l31]        = a01[r];
            X[(32 + m) * 64 + l31]      = a10[r];
            X[(32 + m) * 64 + 32 + l31] = a11[r];
        }
    }
    __syncthreads();
    if (kg == 0) {
#pragma unroll
        for (int r = 0; r < 16; ++r) {
            const int m = (r & 3) + 8 * (r >> 2) + 4 * hf;
            const int domA = edom_s[m];
            const int domB = edom_s[32 + m];
            atomicAdd(&msg[domA * 64 + l31],      a00[r] + X[m * 64 + l31]);
            atomicAdd(&msg[domA * 64 + 32 + l31], a01[r] + X[m * 64 + 32 + l31]);
            atomicAdd(&msg[domB * 64 + l31],      a10[r] + X[(32 + m) * 64 + l31]);
            atomicAdd(&msg[domB * 64 + 32 + l31], a11[r] + X[(32 + m) * 64 + 32 + l31]);
        }
    }
}

// step-1 update: h_h = f16(selu(msg@Wu0 + bu0 + h_h)); zeroes msg (4 nodes/block)
__global__ void node_update_kernel(float* __restrict__ msg, const float* __restrict__ Wu,
                                   const float* __restrict__ bu, _Float16* __restrict__ h_h) {
    __shared__ float ms[4][68];
    int t = threadIdx.x;
    int nb = blockIdx.x * 4;
    int ln = t >> 6, i = t & 63;
    int o = (nb + ln) * H + i;
    ms[ln][i] = msg[o];
    msg[o] = 0.0f;                       // ready for edge step 2 / replay
    __syncthreads();
    float s = bu[i];
#pragma unroll
    for (int k = 0; k < H; ++k) s = fmaf(ms[ln][k], Wu[k * H + i], s);
    h_h[o] = (_Float16)selu_f(s + (float)h_h[o]);
}

// fused step-2 tail: hn = selu(msg@Wu1+bu1+h_h); ae = hn@Wae+bae;
// aa = selu(ae@WR+bR); atomicAdd gsum[gid[n]]   (R3-proven fusion + f16 h)
__global__ void upd2_embed_readout(const float* __restrict__ msg, const float* __restrict__ Wu,
                                   const float* __restrict__ bu, const _Float16* __restrict__ h_h,
                                   const float* __restrict__ Wae, const float* __restrict__ bae,
                                   const float* __restrict__ WR, const float* __restrict__ bR,
                                   const int* __restrict__ gid, float* __restrict__ gsum) {
    __shared__ float ms[4][68];
    __shared__ float hn[4][68];
    __shared__ float ae[4][68];
    int t = threadIdx.x;
    int nb = blockIdx.x * 4;
    int ln = t >> 6, i = t & 63;
    int o = (nb + ln) * H + i;
    ms[ln][i] = msg[o];
    __syncthreads();
    float s = bu[i];
#pragma unroll
    for (int k = 0; k < H; ++k) s = fmaf(ms[ln][k], Wu[k * H + i], s);
    hn[ln][i] = selu_f(s + (float)h_h[o]);
    __syncthreads();
    float s2 = bae[i];
#pragma unroll
    for (int k = 0; k < H; ++k) s2 = fmaf(hn[ln][k], Wae[k * H + i], s2);
    ae[ln][i] = s2;
    __syncthreads();
    float s3 = bR[i];
#pragma unroll
    for (int k = 0; k < H; ++k) s3 = fmaf(ae[ln][k], WR[k * H + i], s3);
    atomicAdd(&gsum[gid[nb + ln] * H + i], selu_f(s3));
}

// per graph: ge = tanh(gsum); mo = relu(ge @ Wmlp + bmlp); out = mo @ Wout + bout
__global__ void final_kernel(const float* __restrict__ gsum, const float* __restrict__ Wmlp,
                             const float* __restrict__ bmlp, const float* __restrict__ Wout,
                             const float* __restrict__ bout, float* __restrict__ out) {
    __shared__ float ge[64];
    int g = blockIdx.x, i = threadIdx.x;
    ge[i] = tanhf(gsum[g * H + i]);
    __syncthreads();
    float s = bmlp[i];
#pragma unroll
    for (int k = 0; k < H; ++k) s = fmaf(ge[k], Wmlp[k * H + i], s);
    float mo = fmaxf(s, 0.0f) * Wout[i];
#pragma unroll
    for (int off = 32; off > 0; off >>= 1) mo += __shfl_down(mo, off);
    if (i == 0) out[g] = mo + bout[0];
}

extern "C" void kernel_launch(void* const* d_in, const int* in_sizes, int n_in,
                              void* d_out, int out_size, void* d_ws, size_t ws_size,
                              hipStream_t stream) {
    const float* nf   = (const float*)d_in[0];
    const float* ef   = (const float*)d_in[1];
    const int*   ed   = (const int*)d_in[2];   // edge_domain (scatter dest)
    const int*   er   = (const int*)d_in[3];   // edge_range  (gather src)
    const int*   gid  = (const int*)d_in[4];
    const float* Wm   = (const float*)d_in[5];
    const float* bm   = (const float*)d_in[6];
    const float* Ew   = (const float*)d_in[7];
    const float* Wu0  = (const float*)d_in[8];
    const float* bu0  = (const float*)d_in[9];
    const float* Wu1  = (const float*)d_in[10];
    const float* bu1  = (const float*)d_in[11];
    const float* Wae  = (const float*)d_in[12];
    const float* bae  = (const float*)d_in[13];
    const float* WR   = (const float*)d_in[14];
    const float* bR   = (const float*)d_in[15];
    const float* Wmlp = (const float*)d_in[16];
    const float* bmlp = (const float*)d_in[17];
    const float* Wout = (const float*)d_in[18];
    const float* bout = (const float*)d_in[19];
    float* out = (float*)d_out;

    float* ws = (float*)d_ws;
    float*    msg  = ws + 1280000;                    // 1,280,000 f32
    float*    gsum = ws + 2560000;                    // 32,768 f32
    unsigned* mlp2 = (unsigned*)(ws + 2592768);       // 32*40000 u32 (f16x2 pairs)
    _Float16* h_h  = (_Float16*)(ws + 3872768);       // 1,280,000 f16
    _Float16* ewb  = (_Float16*)(ws + 4512768);       // 262,144 f16

    prep_kernel<<<7035, 256, 0, stream>>>(nf, ef, Wm, bm, Ew, h_h, mlp2, ewb, msg, gsum);

    edge_message_mfma<<<625, 128, 0, stream>>>(h_h, mlp2, ed, er, ewb, msg);
    node_update_kernel<<<NN / 4, 256, 0, stream>>>(msg, Wu0, bu0, h_h);
    edge_message_mfma<<<625, 128, 0, stream>>>(h_h, mlp2, ed, er, ewb, msg);
    upd2_embed_readout<<<NN / 4, 256, 0, stream>>>(msg, Wu1, bu1, h_h,
                                                   Wae, bae, WR, bR, gid, gsum);

    final_kernel<<<NB, 64, 0, stream>>>(gsum, Wmlp, bmlp, Wout, bout, out);
}

// Round 14
// 127.794 us; speedup vs baseline: 1.1876x; 1.0019x over previous
//
#include <hip/hip_runtime.h>
#include <math.h>

#define NN 20000   // nodes
#define NE 40000   // edges
#define H 64
#define F_ATOM 62
#define F_BOND 6
#define NB 512     // graphs

typedef _Float16 f16x8 __attribute__((ext_vector_type(8)));
typedef float f32x16 __attribute__((ext_vector_type(16)));

__device__ __forceinline__ float selu_f(float x) {
    const float scale = 1.0507009873554805f;
    const float alpha = 1.6732632423543772f;
    return scale * (x > 0.0f ? x : alpha * (__expf(x) - 1.0f));
}

__device__ __forceinline__ f16x8 splat8h(_Float16 x) {
    union { _Float16 h[2]; unsigned u; } p;
    p.h[0] = x; p.h[1] = x;
    union { unsigned u[4]; f16x8 v; } r;
    r.u[0] = p.u; r.u[1] = p.u; r.u[2] = p.u; r.u[3] = p.u;
    return r.v;
}

// Fused prep, role by blockIdx (256 threads each) — round-8 structure (PASSED),
// now h is f16-ONLY (no f32 mirror):
// [0,625)      : mlp2[kkpair][e] = packed f16x2 {relu(ef@Wm+bm)[2p], [2p+1]} via LDS transpose
// [625,5625)   : h_h = f16(pad(nf))
// [5625,5753)  : ewb = f16(Ew) in B-fragment-linear order
// [5753,7003)  : zero msg; [7003,7035): zero gsum
__global__ void prep_kernel(const float* __restrict__ nf, const float* __restrict__ ef,
                            const float* __restrict__ Wm, const float* __restrict__ bm,
                            const float* __restrict__ Ew,
                            _Float16* __restrict__ h_h,
                            unsigned* __restrict__ mlp2, _Float16* __restrict__ ewb,
                            float* __restrict__ msg, float* __restrict__ gsum) {
    const int bid = blockIdx.x;
    const int t = threadIdx.x;
    if (bid < 625) {
        __shared__ float st[64][65];
        const int el = t & 63;
        const int ig = t >> 6;                 // wave id; i = ig*16+p wave-uniform
        const int e = bid * 64 + el;
        const float* efe = ef + e * F_BOND;
        const float e0 = efe[0], e1 = efe[1], e2 = efe[2];
        const float e3 = efe[3], e4 = efe[4], e5 = efe[5];
#pragma unroll
        for (int p = 0; p < 16; ++p) {
            const int i = ig * 16 + p;
            float s = bm[i];
            s = fmaf(e0, Wm[0 * H + i], s);
            s = fmaf(e1, Wm[1 * H + i], s);
            s = fmaf(e2, Wm[2 * H + i], s);
            s = fmaf(e3, Wm[3 * H + i], s);
            s = fmaf(e4, Wm[4 * H + i], s);
            s = fmaf(e5, Wm[5 * H + i], s);
            st[i][el] = fmaxf(s, 0.0f);
        }
        __syncthreads();
        const int p = t >> 3;                  // kk-pair 0..31
        const int ch = t & 7;                  // 8-edge chunk
#pragma unroll
        for (int j = 0; j < 8; ++j) {
            const int e_l = ch * 8 + j;
            union { unsigned u; _Float16 hh[2]; } pk;
            pk.hh[0] = (_Float16)st[2 * p][e_l];
            pk.hh[1] = (_Float16)st[2 * p + 1][e_l];
            mlp2[(size_t)p * NE + bid * 64 + e_l] = pk.u;
        }
    } else if (bid < 5625) {
        int idx = (bid - 625) * 256 + t;
        int n = idx >> 6, c = idx & 63;
        h_h[idx] = (_Float16)((c < F_ATOM) ? nf[n * F_ATOM + c] : 0.0f);
    } else if (bid < 5753) {
        int tid = (bid - 5625) * 256 + t;      // 0..32767
        int l = tid & 63;
        int nt = (tid >> 6) & 1;
        int c = tid >> 7;                      // 0..255 = kk*4 + cq
        int kk = c >> 2;
        int jbase = (c & 3) * 16 + (l >> 5) * 8;
        int i = nt * 32 + (l & 31);
        const float* src = Ew + kk * 4096 + i * 64 + jbase;
        _Float16* dst = ewb + tid * 8;
#pragma unroll
        for (int u = 0; u < 8; ++u) dst[u] = (_Float16)src[u];
    } else if (bid < 7003) {
        int idx = (bid - 5753) * 256 + t;
        reinterpret_cast<float4*>(msg)[idx] = make_float4(0.f, 0.f, 0.f, 0.f);
    } else {
        int idx = (bid - 7003) * 256 + t;
        reinterpret_cast<float4*>(gsum)[idx] = make_float4(0.f, 0.f, 0.f, 0.f);
    }
}

// Edge message — round-12 verbatim (PASSED, 6.1e-5) + s_setprio(1) around the
// MFMA cluster (T5: barrier-free waves have role diversity). Block = 128 thr =
// 2 waves; wave kg owns kk [kg*32,+32) and a PRIVATE 3x8KB LDS ring; counted
// per-wave vmcnt(8), no inter-wave barrier in hot loop; LDS merge + 1 atomic round.
__global__ __launch_bounds__(128, 2) void edge_message_mfma(
    const _Float16* __restrict__ h_h, const unsigned* __restrict__ mlp2,
    const int* __restrict__ ed, const int* __restrict__ er,
    const _Float16* __restrict__ ewb, float* __restrict__ msg)
{
    __shared__ char sm[49152];            // 48 KB: wave kg -> [kg*24K, +24K) 3-buf ring; merge X reuses [0,16K)
    __shared__ int edom_s[64];

    const int t = threadIdx.x;
    const int lane = t & 63;
    const int kg = t >> 6;                // K-group 0..1 (kk in [kg*32, kg*32+32))
    const int l31 = lane & 31;
    const int hf = lane >> 5;
    const int eb = blockIdx.x * 64;

    if (t < 64) edom_s[t] = ed[eb + t];   // loaded by wave 0 (=kg 0), read only by kg 0

    const int eA = eb + l31;              // M-tile 0 row (exact: 625*64 == NE)
    const int eB = eA + 32;               // M-tile 1 row
    const int gA = er[eA], gB = er[eB];

    // hj fragments (f16): j = cq*16 + hf*8 + tt   (proven mapping)
    f16x8 hjA[4], hjB[4];
#pragma unroll
    for (int cq = 0; cq < 4; ++cq) {
        hjA[cq] = *reinterpret_cast<const f16x8*>(h_h + gA * 64 + cq * 16 + hf * 8);
        hjB[cq] = *reinterpret_cast<const f16x8*>(h_h + gB * 64 + cq * 16 + hf * 8);
    }

    // mlp pairs: kg covers pairs [kg*16, kg*16+16); pair pp -> kk {2pp, 2pp+1}
    unsigned mvA[16], mvB[16];
#pragma unroll
    for (int pp = 0; pp < 16; ++pp) {
        mvA[pp] = mlp2[(size_t)(kg * 16 + pp) * NE + eA];
        mvB[pp] = mlp2[(size_t)(kg * 16 + pp) * NE + eB];
    }

    // drain pre-loads so vmcnt counts ONLY stage DMAs from here on
    asm volatile("s_waitcnt vmcnt(0)" ::: "memory");

    char* wbase = sm + kg * 24576;
    // stage 8KB slice kk = kg*32+s into private ring buf (s%3); whole wave stages it
    auto stage = [&](int s) {
        const char* gs = reinterpret_cast<const char*>(ewb) +
                         ((size_t)(kg * 32 + s) << 13) + lane * 16;
        char* lb = wbase + (s % 3) * 8192 + lane * 16;
#pragma unroll
        for (int r = 0; r < 8; ++r) {
            __builtin_amdgcn_global_load_lds(
                (const __attribute__((address_space(1))) void*)(gs + r * 1024),
                (__attribute__((address_space(3))) void*)(lb + r * 1024),
                16, 0, 0);
        }
    };

    f32x16 a00, a01, a10, a11;
#pragma unroll
    for (int i = 0; i < 16; ++i) { a00[i] = 0.f; a01[i] = 0.f; a10[i] = 0.f; a11[i] = 0.f; }

    stage(0);
    stage(1);                             // 16 DMA ops in flight

#pragma unroll
    for (int s = 0; s < 32; ++s) {
        if (s < 31) asm volatile("s_waitcnt vmcnt(8)" ::: "memory");  // stage(s) retired
        else        asm volatile("s_waitcnt vmcnt(0)" ::: "memory");  // last slice
        if (s < 30) stage(s + 2);         // buf (s+2)%3 == (s-1)%3, reads finished in iter s-1
        const char* buf = wbase + (s % 3) * 8192;
        union { unsigned u; _Float16 hh[2]; } ua, ub;
        ua.u = mvA[s >> 1]; ub.u = mvB[s >> 1];
        f16x8 sA = splat8h(ua.hh[s & 1]);
        f16x8 sB = splat8h(ub.hh[s & 1]);
        __builtin_amdgcn_s_setprio(1);
#pragma unroll
        for (int cq = 0; cq < 4; ++cq) {
            f16x8 b0 = *reinterpret_cast<const f16x8*>(buf + (cq * 2 + 0) * 1024 + lane * 16);
            f16x8 b1 = *reinterpret_cast<const f16x8*>(buf + (cq * 2 + 1) * 1024 + lane * 16);
            f16x8 aA = sA * hjA[cq];
            f16x8 aB = sB * hjB[cq];
            a00 = __builtin_amdgcn_mfma_f32_32x32x16_f16(aA, b0, a00, 0, 0, 0);
            a01 = __builtin_amdgcn_mfma_f32_32x32x16_f16(aA, b1, a01, 0, 0, 0);
            a10 = __builtin_amdgcn_mfma_f32_32x32x16_f16(aB, b0, a10, 0, 0, 0);
            a11 = __builtin_amdgcn_mfma_f32_32x32x16_f16(aB, b1, a11, 0, 0, 0);
        }
        __builtin_amdgcn_s_setprio(0);
    }

    // ---- K-partial merge in LDS (stage area now dead; all DMA drained) ----
    // C/D row formula (proven): m = (r&3) + 8*(r>>2) + 4*hf
    float* X = reinterpret_cast<float*>(sm);           // 16 KB: [64 e_loc][64 col]
    __syncthreads();                      // both waves done computing
    if (kg == 1) {
#pragma unroll
        for (int r = 0; r < 16; ++r) {
            const int m = (r & 3) + 8 * (r >> 2) + 4 * hf;
            X[m * 64 + l31]             = a00[r];
            X[m * 64 + 32 + l31]        = a01[r];
            X[(32 + m) * 64 + l31]      = a10[r];
            X[(32 + m) * 64 + 32 + l31] = a11[r];
        }
    }
    __syncthreads();
    if (kg == 0) {
#pragma unroll
        for (int r = 0; r < 16; ++r) {
            const int m = (r & 3) + 8 * (r >> 2) + 4 * hf;
            const int domA = edom_s[m];
            const int domB = edom_s[32 + m];
            atomicAdd(&msg[domA * 64 + l31],      a00[r] + X[m * 64 + l31]);
            atomicAdd(&msg[domA * 64 + 32 + l31], a01[r] + X[m * 64 + 32 + l31]);
            atomicAdd(&msg[domB * 64 + l31],      a10[r] + X[(32 + m) * 64 + l31]);
            atomicAdd(&msg[domB * 64 + 32 + l31], a11[r] + X[(32 + m) * 64 + 32 + l31]);
        }
    }
}

// step-1 update: h_h = f16(selu(msg@Wu0 + bu0 + h_h)); zeroes msg (4 nodes/block)
__global__ void node_update_kernel(float* __restrict__ msg, const float* __restrict__ Wu,
                                   const float* __restrict__ bu, _Float16* __restrict__ h_h) {
    __shared__ float ms[4][68];
    int t = threadIdx.x;
    int nb = blockIdx.x * 4;
    int ln = t >> 6, i = t & 63;
    int o = (nb + ln) * H + i;
    ms[ln][i] = msg[o];
    msg[o] = 0.0f;                       // ready for edge step 2 / replay
    __syncthreads();
    float s = bu[i];
#pragma unroll
    for (int k = 0; k < H; ++k) s = fmaf(ms[ln][k], Wu[k * H + i], s);
    h_h[o] = (_Float16)selu_f(s + (float)h_h[o]);
}

// fused step-2 tail: hn = selu(msg@Wu1+bu1+h_h); ae = hn@Wae+bae;
// aa = selu(ae@WR+bR); atomicAdd gsum[gid[n]]   (R3-proven fusion + f16 h)
__global__ void upd2_embed_readout(const float* __restrict__ msg, const float* __restrict__ Wu,
                                   const float* __restrict__ bu, const _Float16* __restrict__ h_h,
                                   const float* __restrict__ Wae, const float* __restrict__ bae,
                                   const float* __restrict__ WR, const float* __restrict__ bR,
                                   const int* __restrict__ gid, float* __restrict__ gsum) {
    __shared__ float ms[4][68];
    __shared__ float hn[4][68];
    __shared__ float ae[4][68];
    int t = threadIdx.x;
    int nb = blockIdx.x * 4;
    int ln = t >> 6, i = t & 63;
    int o = (nb + ln) * H + i;
    ms[ln][i] = msg[o];
    __syncthreads();
    float s = bu[i];
#pragma unroll
    for (int k = 0; k < H; ++k) s = fmaf(ms[ln][k], Wu[k * H + i], s);
    hn[ln][i] = selu_f(s + (float)h_h[o]);
    __syncthreads();
    float s2 = bae[i];
#pragma unroll
    for (int k = 0; k < H; ++k) s2 = fmaf(hn[ln][k], Wae[k * H + i], s2);
    ae[ln][i] = s2;
    __syncthreads();
    float s3 = bR[i];
#pragma unroll
    for (int k = 0; k < H; ++k) s3 = fmaf(ae[ln][k], WR[k * H + i], s3);
    atomicAdd(&gsum[gid[nb + ln] * H + i], selu_f(s3));
}

// per graph: ge = tanh(gsum); mo = relu(ge @ Wmlp + bmlp); out = mo @ Wout + bout
__global__ void final_kernel(const float* __restrict__ gsum, const float* __restrict__ Wmlp,
                             const float* __restrict__ bmlp, const float* __restrict__ Wout,
                             const float* __restrict__ bout, float* __restrict__ out) {
    __shared__ float ge[64];
    int g = blockIdx.x, i = threadIdx.x;
    ge[i] = tanhf(gsum[g * H + i]);
    __syncthreads();
    float s = bmlp[i];
#pragma unroll
    for (int k = 0; k < H; ++k) s = fmaf(ge[k], Wmlp[k * H + i], s);
    float mo = fmaxf(s, 0.0f) * Wout[i];
#pragma unroll
    for (int off = 32; off > 0; off >>= 1) mo += __shfl_down(mo, off);
    if (i == 0) out[g] = mo + bout[0];
}

extern "C" void kernel_launch(void* const* d_in, const int* in_sizes, int n_in,
                              void* d_out, int out_size, void* d_ws, size_t ws_size,
                              hipStream_t stream) {
    const float* nf   = (const float*)d_in[0];
    const float* ef   = (const float*)d_in[1];
    const int*   ed   = (const int*)d_in[2];   // edge_domain (scatter dest)
    const int*   er   = (const int*)d_in[3];   // edge_range  (gather src)
    const int*   gid  = (const int*)d_in[4];
    const float* Wm   = (const float*)d_in[5];
    const float* bm   = (const float*)d_in[6];
    const float* Ew   = (const float*)d_in[7];
    const float* Wu0  = (const float*)d_in[8];
    const float* bu0  = (const float*)d_in[9];
    const float* Wu1  = (const float*)d_in[10];
    const float* bu1  = (const float*)d_in[11];
    const float* Wae  = (const float*)d_in[12];
    const float* bae  = (const float*)d_in[13];
    const float* WR   = (const float*)d_in[14];
    const float* bR   = (const float*)d_in[15];
    const float* Wmlp = (const float*)d_in[16];
    const float* bmlp = (const float*)d_in[17];
    const float* Wout = (const float*)d_in[18];
    const float* bout = (const float*)d_in[19];
    float* out = (float*)d_out;

    float* ws = (float*)d_ws;
    float*    msg  = ws + 1280000;                    // 1,280,000 f32
    float*    gsum = ws + 2560000;                    // 32,768 f32
    unsigned* mlp2 = (unsigned*)(ws + 2592768);       // 32*40000 u32 (f16x2 pairs)
    _Float16* h_h  = (_Float16*)(ws + 3872768);       // 1,280,000 f16
    _Float16* ewb  = (_Float16*)(ws + 4512768);       // 262,144 f16

    prep_kernel<<<7035, 256, 0, stream>>>(nf, ef, Wm, bm, Ew, h_h, mlp2, ewb, msg, gsum);

    edge_message_mfma<<<625, 128, 0, stream>>>(h_h, mlp2, ed, er, ewb, msg);
    node_update_kernel<<<NN / 4, 256, 0, stream>>>(msg, Wu0, bu0, h_h);
    edge_message_mfma<<<625, 128, 0, stream>>>(h_h, mlp2, ed, er, ewb, msg);
    upd2_embed_readout<<<NN / 4, 256, 0, stream>>>(msg, Wu1, bu1, h_h,
                                                   Wae, bae, WR, bR, gid, gsum);

    final_kernel<<<NB, 64, 0, stream>>>(gsum, Wmlp, bmlp, Wout, bout, out);
}

// Round 15
// 113.676 us; speedup vs baseline: 1.3351x; 1.1242x over previous
//
#include <hip/hip_runtime.h>
#include <math.h>

#define NN 20000   // nodes
#define NE 40000   // edges
#define H 64
#define F_ATOM 62
#define F_BOND 6
#define NB 512     // graphs

typedef _Float16 f16x8 __attribute__((ext_vector_type(8)));
typedef float f32x16 __attribute__((ext_vector_type(16)));

__device__ __forceinline__ float selu_f(float x) {
    const float scale = 1.0507009873554805f;
    const float alpha = 1.6732632423543772f;
    return scale * (x > 0.0f ? x : alpha * (__expf(x) - 1.0f));
}

__device__ __forceinline__ f16x8 splat8h(_Float16 x) {
    union { _Float16 h[2]; unsigned u; } p;
    p.h[0] = x; p.h[1] = x;
    union { unsigned u[4]; f16x8 v; } r;
    r.u[0] = p.u; r.u[1] = p.u; r.u[2] = p.u; r.u[3] = p.u;
    return r.v;
}

// Fused prep, role by blockIdx (256 threads each) — round-14 verbatim (PASSED):
// [0,625)      : mlp2[kkpair][e] = packed f16x2 {relu(ef@Wm+bm)[2p], [2p+1]} via LDS transpose
// [625,5625)   : h_h = f16(pad(nf))
// [5625,5753)  : ewb = f16(Ew) in B-fragment-linear order
// [5753,7003)  : zero msg; [7003,7035): zero gsum
__global__ void prep_kernel(const float* __restrict__ nf, const float* __restrict__ ef,
                            const float* __restrict__ Wm, const float* __restrict__ bm,
                            const float* __restrict__ Ew,
                            _Float16* __restrict__ h_h,
                            unsigned* __restrict__ mlp2, _Float16* __restrict__ ewb,
                            float* __restrict__ msg, float* __restrict__ gsum) {
    const int bid = blockIdx.x;
    const int t = threadIdx.x;
    if (bid < 625) {
        __shared__ float st[64][65];
        const int el = t & 63;
        const int ig = t >> 6;                 // wave id; i = ig*16+p wave-uniform
        const int e = bid * 64 + el;
        const float* efe = ef + e * F_BOND;
        const float e0 = efe[0], e1 = efe[1], e2 = efe[2];
        const float e3 = efe[3], e4 = efe[4], e5 = efe[5];
#pragma unroll
        for (int p = 0; p < 16; ++p) {
            const int i = ig * 16 + p;
            float s = bm[i];
            s = fmaf(e0, Wm[0 * H + i], s);
            s = fmaf(e1, Wm[1 * H + i], s);
            s = fmaf(e2, Wm[2 * H + i], s);
            s = fmaf(e3, Wm[3 * H + i], s);
            s = fmaf(e4, Wm[4 * H + i], s);
            s = fmaf(e5, Wm[5 * H + i], s);
            st[i][el] = fmaxf(s, 0.0f);
        }
        __syncthreads();
        const int p = t >> 3;                  // kk-pair 0..31
        const int ch = t & 7;                  // 8-edge chunk
#pragma unroll
        for (int j = 0; j < 8; ++j) {
            const int e_l = ch * 8 + j;
            union { unsigned u; _Float16 hh[2]; } pk;
            pk.hh[0] = (_Float16)st[2 * p][e_l];
            pk.hh[1] = (_Float16)st[2 * p + 1][e_l];
            mlp2[(size_t)p * NE + bid * 64 + e_l] = pk.u;
        }
    } else if (bid < 5625) {
        int idx = (bid - 625) * 256 + t;
        int n = idx >> 6, c = idx & 63;
        h_h[idx] = (_Float16)((c < F_ATOM) ? nf[n * F_ATOM + c] : 0.0f);
    } else if (bid < 5753) {
        int tid = (bid - 5625) * 256 + t;      // 0..32767
        int l = tid & 63;
        int nt = (tid >> 6) & 1;
        int c = tid >> 7;                      // 0..255 = kk*4 + cq
        int kk = c >> 2;
        int jbase = (c & 3) * 16 + (l >> 5) * 8;
        int i = nt * 32 + (l & 31);
        const float* src = Ew + kk * 4096 + i * 64 + jbase;
        _Float16* dst = ewb + tid * 8;
#pragma unroll
        for (int u = 0; u < 8; ++u) dst[u] = (_Float16)src[u];
    } else if (bid < 7003) {
        int idx = (bid - 5753) * 256 + t;
        reinterpret_cast<float4*>(msg)[idx] = make_float4(0.f, 0.f, 0.f, 0.f);
    } else {
        int idx = (bid - 7003) * 256 + t;
        reinterpret_cast<float4*>(gsum)[idx] = make_float4(0.f, 0.f, 0.f, 0.f);
    }
}

// Edge message — round-14 verbatim (PASSED). Block = 128 thr = 2 waves; wave kg
// owns kk [kg*32,+32) and a PRIVATE 3x8KB LDS ring; counted per-wave vmcnt(8),
// no inter-wave barrier in hot loop; setprio around MFMA; LDS merge + 1 atomic round.
__global__ __launch_bounds__(128, 2) void edge_message_mfma(
    const _Float16* __restrict__ h_h, const unsigned* __restrict__ mlp2,
    const int* __restrict__ ed, const int* __restrict__ er,
    const _Float16* __restrict__ ewb, float* __restrict__ msg)
{
    __shared__ char sm[49152];            // 48 KB: wave kg -> [kg*24K, +24K) 3-buf ring; merge X reuses [0,16K)
    __shared__ int edom_s[64];

    const int t = threadIdx.x;
    const int lane = t & 63;
    const int kg = t >> 6;                // K-group 0..1 (kk in [kg*32, kg*32+32))
    const int l31 = lane & 31;
    const int hf = lane >> 5;
    const int eb = blockIdx.x * 64;

    if (t < 64) edom_s[t] = ed[eb + t];   // loaded by wave 0 (=kg 0), read only by kg 0

    const int eA = eb + l31;              // M-tile 0 row (exact: 625*64 == NE)
    const int eB = eA + 32;               // M-tile 1 row
    const int gA = er[eA], gB = er[eB];

    // hj fragments (f16): j = cq*16 + hf*8 + tt   (proven mapping)
    f16x8 hjA[4], hjB[4];
#pragma unroll
    for (int cq = 0; cq < 4; ++cq) {
        hjA[cq] = *reinterpret_cast<const f16x8*>(h_h + gA * 64 + cq * 16 + hf * 8);
        hjB[cq] = *reinterpret_cast<const f16x8*>(h_h + gB * 64 + cq * 16 + hf * 8);
    }

    // mlp pairs: kg covers pairs [kg*16, kg*16+16); pair pp -> kk {2pp, 2pp+1}
    unsigned mvA[16], mvB[16];
#pragma unroll
    for (int pp = 0; pp < 16; ++pp) {
        mvA[pp] = mlp2[(size_t)(kg * 16 + pp) * NE + eA];
        mvB[pp] = mlp2[(size_t)(kg * 16 + pp) * NE + eB];
    }

    // drain pre-loads so vmcnt counts ONLY stage DMAs from here on
    asm volatile("s_waitcnt vmcnt(0)" ::: "memory");

    char* wbase = sm + kg * 24576;
    // stage 8KB slice kk = kg*32+s into private ring buf (s%3); whole wave stages it
    auto stage = [&](int s) {
        const char* gs = reinterpret_cast<const char*>(ewb) +
                         ((size_t)(kg * 32 + s) << 13) + lane * 16;
        char* lb = wbase + (s % 3) * 8192 + lane * 16;
#pragma unroll
        for (int r = 0; r < 8; ++r) {
            __builtin_amdgcn_global_load_lds(
                (const __attribute__((address_space(1))) void*)(gs + r * 1024),
                (__attribute__((address_space(3))) void*)(lb + r * 1024),
                16, 0, 0);
        }
    };

    f32x16 a00, a01, a10, a11;
#pragma unroll
    for (int i = 0; i < 16; ++i) { a00[i] = 0.f; a01[i] = 0.f; a10[i] = 0.f; a11[i] = 0.f; }

    stage(0);
    stage(1);                             // 16 DMA ops in flight

#pragma unroll
    for (int s = 0; s < 32; ++s) {
        if (s < 31) asm volatile("s_waitcnt vmcnt(8)" ::: "memory");  // stage(s) retired
        else        asm volatile("s_waitcnt vmcnt(0)" ::: "memory");  // last slice
        if (s < 30) stage(s + 2);         // buf (s+2)%3 == (s-1)%3, reads finished in iter s-1
        const char* buf = wbase + (s % 3) * 8192;
        union { unsigned u; _Float16 hh[2]; } ua, ub;
        ua.u = mvA[s >> 1]; ub.u = mvB[s >> 1];
        f16x8 sA = splat8h(ua.hh[s & 1]);
        f16x8 sB = splat8h(ub.hh[s & 1]);
        __builtin_amdgcn_s_setprio(1);
#pragma unroll
        for (int cq = 0; cq < 4; ++cq) {
            f16x8 b0 = *reinterpret_cast<const f16x8*>(buf + (cq * 2 + 0) * 1024 + lane * 16);
            f16x8 b1 = *reinterpret_cast<const f16x8*>(buf + (cq * 2 + 1) * 1024 + lane * 16);
            f16x8 aA = sA * hjA[cq];
            f16x8 aB = sB * hjB[cq];
            a00 = __builtin_amdgcn_mfma_f32_32x32x16_f16(aA, b0, a00, 0, 0, 0);
            a01 = __builtin_amdgcn_mfma_f32_32x32x16_f16(aA, b1, a01, 0, 0, 0);
            a10 = __builtin_amdgcn_mfma_f32_32x32x16_f16(aB, b0, a10, 0, 0, 0);
            a11 = __builtin_amdgcn_mfma_f32_32x32x16_f16(aB, b1, a11, 0, 0, 0);
        }
        __builtin_amdgcn_s_setprio(0);
    }

    // ---- K-partial merge in LDS (stage area now dead; all DMA drained) ----
    // C/D row formula (proven): m = (r&3) + 8*(r>>2) + 4*hf
    float* X = reinterpret_cast<float*>(sm);           // 16 KB: [64 e_loc][64 col]
    __syncthreads();                      // both waves done computing
    if (kg == 1) {
#pragma unroll
        for (int r = 0; r < 16; ++r) {
            const int m = (r & 3) + 8 * (r >> 2) + 4 * hf;
            X[m * 64 + l31]             = a00[r];
            X[m * 64 + 32 + l31]        = a01[r];
            X[(32 + m) * 64 + l31]      = a10[r];
            X[(32 + m) * 64 + 32 + l31] = a11[r];
        }
    }
    __syncthreads();
    if (kg == 0) {
#pragma unroll
        for (int r = 0; r < 16; ++r) {
            const int m = (r & 3) + 8 * (r >> 2) + 4 * hf;
            const int domA = edom_s[m];
            const int domB = edom_s[32 + m];
            atomicAdd(&msg[domA * 64 + l31],      a00[r] + X[m * 64 + l31]);
            atomicAdd(&msg[domA * 64 + 32 + l31], a01[r] + X[m * 64 + 32 + l31]);
            atomicAdd(&msg[domB * 64 + l31],      a10[r] + X[(32 + m) * 64 + l31]);
            atomicAdd(&msg[domB * 64 + 32 + l31], a11[r] + X[(32 + m) * 64 + 32 + l31]);
        }
    }
}

// step-1 update, ILP version: 32 nodes/block, thread = (col i, 8-node group) ->
// 8 independent fma chains sharing each W load. Numerics identical to R14
// (same bu seed, same k-order). Zeroes msg for step 2 / replay.
__global__ __launch_bounds__(256) void node_update_kernel(
    float* __restrict__ msg, const float* __restrict__ Wu,
    const float* __restrict__ bu, _Float16* __restrict__ h_h) {
    __shared__ float ms[32][65];
    const int t = threadIdx.x;
    const int nb = blockIdx.x * 32;
    // stage msg (32x64) + zero it: 512 float4s, 2 per thread
#pragma unroll
    for (int r = 0; r < 2; ++r) {
        int idx = r * 256 + t;
        int n = idx >> 4, c4 = (idx & 15) * 4;
        float4* src = reinterpret_cast<float4*>(msg + (size_t)(nb + n) * 64 + c4);
        float4 v = *src;
        *src = make_float4(0.f, 0.f, 0.f, 0.f);
        ms[n][c4 + 0] = v.x; ms[n][c4 + 1] = v.y;
        ms[n][c4 + 2] = v.z; ms[n][c4 + 3] = v.w;
    }
    __syncthreads();
    const int i = t & 63;
    const int n0 = (t >> 6) * 8;          // node group base
    float acc[8];
#pragma unroll
    for (int j = 0; j < 8; ++j) acc[j] = bu[i];
#pragma unroll 8
    for (int k = 0; k < 64; ++k) {
        float w = Wu[k * 64 + i];
#pragma unroll
        for (int j = 0; j < 8; ++j) acc[j] = fmaf(ms[n0 + j][k], w, acc[j]);
    }
#pragma unroll
    for (int j = 0; j < 8; ++j) {
        int o = (nb + n0 + j) * 64 + i;
        h_h[o] = (_Float16)selu_f(acc[j] + (float)h_h[o]);
    }
}

// fused step-2 tail, ILP version: 32 nodes/block, 8 accs/thread per stage.
// hn = selu(msg@Wu1+bu1+h_h); ae = hn@Wae+bae; aa = selu(ae@WR+bR); atomic gsum.
__global__ __launch_bounds__(256) void upd2_embed_readout(
    const float* __restrict__ msg, const float* __restrict__ Wu,
    const float* __restrict__ bu, const _Float16* __restrict__ h_h,
    const float* __restrict__ Wae, const float* __restrict__ bae,
    const float* __restrict__ WR, const float* __restrict__ bR,
    const int* __restrict__ gid, float* __restrict__ gsum) {
    __shared__ float ms[32][65];
    __shared__ float hn[32][65];
    __shared__ float ae[32][65];
    const int t = threadIdx.x;
    const int nb = blockIdx.x * 32;
#pragma unroll
    for (int r = 0; r < 2; ++r) {
        int idx = r * 256 + t;
        int n = idx >> 4, c4 = (idx & 15) * 4;
        float4 v = *reinterpret_cast<const float4*>(msg + (size_t)(nb + n) * 64 + c4);
        ms[n][c4 + 0] = v.x; ms[n][c4 + 1] = v.y;
        ms[n][c4 + 2] = v.z; ms[n][c4 + 3] = v.w;
    }
    __syncthreads();
    const int i = t & 63;
    const int n0 = (t >> 6) * 8;
    float acc[8];
    // stage 1: hn = selu(ms@Wu + bu + h_h)
#pragma unroll
    for (int j = 0; j < 8; ++j) acc[j] = bu[i];
#pragma unroll 8
    for (int k = 0; k < 64; ++k) {
        float w = Wu[k * 64 + i];
#pragma unroll
        for (int j = 0; j < 8; ++j) acc[j] = fmaf(ms[n0 + j][k], w, acc[j]);
    }
#pragma unroll
    for (int j = 0; j < 8; ++j)
        hn[n0 + j][i] = selu_f(acc[j] + (float)h_h[(nb + n0 + j) * 64 + i]);
    __syncthreads();
    // stage 2: ae = hn@Wae + bae
#pragma unroll
    for (int j = 0; j < 8; ++j) acc[j] = bae[i];
#pragma unroll 8
    for (int k = 0; k < 64; ++k) {
        float w = Wae[k * 64 + i];
#pragma unroll
        for (int j = 0; j < 8; ++j) acc[j] = fmaf(hn[n0 + j][k], w, acc[j]);
    }
#pragma unroll
    for (int j = 0; j < 8; ++j) ae[n0 + j][i] = acc[j];
    __syncthreads();
    // stage 3: aa = selu(ae@WR + bR) -> atomic gsum
#pragma unroll
    for (int j = 0; j < 8; ++j) acc[j] = bR[i];
#pragma unroll 8
    for (int k = 0; k < 64; ++k) {
        float w = WR[k * 64 + i];
#pragma unroll
        for (int j = 0; j < 8; ++j) acc[j] = fmaf(ae[n0 + j][k], w, acc[j]);
    }
#pragma unroll
    for (int j = 0; j < 8; ++j)
        atomicAdd(&gsum[gid[nb + n0 + j] * 64 + i], selu_f(acc[j]));
}

// per graph: ge = tanh(gsum); mo = relu(ge @ Wmlp + bmlp); out = mo @ Wout + bout
__global__ void final_kernel(const float* __restrict__ gsum, const float* __restrict__ Wmlp,
                             const float* __restrict__ bmlp, const float* __restrict__ Wout,
                             const float* __restrict__ bout, float* __restrict__ out) {
    __shared__ float ge[64];
    int g = blockIdx.x, i = threadIdx.x;
    ge[i] = tanhf(gsum[g * H + i]);
    __syncthreads();
    float s = bmlp[i];
#pragma unroll
    for (int k = 0; k < H; ++k) s = fmaf(ge[k], Wmlp[k * H + i], s);
    float mo = fmaxf(s, 0.0f) * Wout[i];
#pragma unroll
    for (int off = 32; off > 0; off >>= 1) mo += __shfl_down(mo, off);
    if (i == 0) out[g] = mo + bout[0];
}

extern "C" void kernel_launch(void* const* d_in, const int* in_sizes, int n_in,
                              void* d_out, int out_size, void* d_ws, size_t ws_size,
                              hipStream_t stream) {
    const float* nf   = (const float*)d_in[0];
    const float* ef   = (const float*)d_in[1];
    const int*   ed   = (const int*)d_in[2];   // edge_domain (scatter dest)
    const int*   er   = (const int*)d_in[3];   // edge_range  (gather src)
    const int*   gid  = (const int*)d_in[4];
    const float* Wm   = (const float*)d_in[5];
    const float* bm   = (const float*)d_in[6];
    const float* Ew   = (const float*)d_in[7];
    const float* Wu0  = (const float*)d_in[8];
    const float* bu0  = (const float*)d_in[9];
    const float* Wu1  = (const float*)d_in[10];
    const float* bu1  = (const float*)d_in[11];
    const float* Wae  = (const float*)d_in[12];
    const float* bae  = (const float*)d_in[13];
    const float* WR   = (const float*)d_in[14];
    const float* bR   = (const float*)d_in[15];
    const float* Wmlp = (const float*)d_in[16];
    const float* bmlp = (const float*)d_in[17];
    const float* Wout = (const float*)d_in[18];
    const float* bout = (const float*)d_in[19];
    float* out = (float*)d_out;

    float* ws = (float*)d_ws;
    float*    msg  = ws + 1280000;                    // 1,280,000 f32
    float*    gsum = ws + 2560000;                    // 32,768 f32
    unsigned* mlp2 = (unsigned*)(ws + 2592768);       // 32*40000 u32 (f16x2 pairs)
    _Float16* h_h  = (_Float16*)(ws + 3872768);       // 1,280,000 f16
    _Float16* ewb  = (_Float16*)(ws + 4512768);       // 262,144 f16

    prep_kernel<<<7035, 256, 0, stream>>>(nf, ef, Wm, bm, Ew, h_h, mlp2, ewb, msg, gsum);

    edge_message_mfma<<<625, 128, 0, stream>>>(h_h, mlp2, ed, er, ewb, msg);
    node_update_kernel<<<NN / 32, 256, 0, stream>>>(msg, Wu0, bu0, h_h);
    edge_message_mfma<<<625, 128, 0, stream>>>(h_h, mlp2, ed, er, ewb, msg);
    upd2_embed_readout<<<NN / 32, 256, 0, stream>>>(msg, Wu1, bu1, h_h,
                                                    Wae, bae, WR, bR, gid, gsum);

    final_kernel<<<NB, 64, 0, stream>>>(gsum, Wmlp, bmlp, Wout, bout, out);
}